// Round 6
// baseline (185.583 us; speedup 1.0000x reference)
//
#include <hip/hip_runtime.h>

#define GAMMA 0.1f
#define MIN_R 0.1f

#define NRP 128                 // nodes per range (power of 2)
#define LOG_NR 7
#define S3 (3 * NRP)            // floats per range slice (384)
#define NB 256                  // blocks for scatter kernel
#define THR_S 256
#define THR_P 512
#define RMAX 1024               // max ranges (n_nodes <= 131072 = 17-bit src)
#define OVCAP 65536             // overflow list capacity (edges)

// ---------------- fused count+reserve+scatter --------------------------------
// gcur[r]: global allocation cursor for bin r (also final count for process).
// pk bin r lives at pk[r*CAP .. r*CAP+CAP).
__global__ __launch_bounds__(THR_S) void scatter_kernel(
    const int* __restrict__ src, const int* __restrict__ dst,
    unsigned* __restrict__ gcur, unsigned* __restrict__ oc,
    unsigned* __restrict__ ovf, unsigned* __restrict__ pk,
    int n_edges, int epb, int R, int CAP)
{
    __shared__ unsigned hist[RMAX];
    const int b = blockIdx.x, t = threadIdx.x;
    const int s0 = b * epb;
    const int s1 = min(s0 + epb, n_edges);

    for (int i = t; i < R; i += THR_S) hist[i] = 0u;
    __syncthreads();

    // pass 1: histogram this slice
    for (int base = s0 + t * 4; base < s1; base += THR_S * 4) {
        if (base + 3 < s1) {
            int4 d4 = *(const int4*)(dst + base);
            atomicAdd(&hist[(unsigned)d4.x >> LOG_NR], 1u);
            atomicAdd(&hist[(unsigned)d4.y >> LOG_NR], 1u);
            atomicAdd(&hist[(unsigned)d4.z >> LOG_NR], 1u);
            atomicAdd(&hist[(unsigned)d4.w >> LOG_NR], 1u);
        } else {
            for (int e = base; e < s1; ++e)
                atomicAdd(&hist[(unsigned)dst[e] >> LOG_NR], 1u);
        }
    }
    __syncthreads();

    // reserve: hist[i] becomes this block's absolute write cursor for bin i
    for (int i = t; i < R; i += THR_S) {
        unsigned c = hist[i];
        hist[i] = c ? atomicAdd(&gcur[i], c) : 0u;
    }
    __syncthreads();

    // pass 2: scatter (dst/src re-read is L2-hot)
    for (int base = s0 + t * 4; base < s1; base += THR_S * 4) {
        if (base + 3 < s1) {
            int4 d4 = *(const int4*)(dst + base);
            int4 s4 = *(const int4*)(src + base);
            #pragma unroll
            for (int k = 0; k < 4; ++k) {
                unsigned d = (unsigned)((k == 0) ? d4.x : (k == 1) ? d4.y : (k == 2) ? d4.z : d4.w);
                unsigned s = (unsigned)((k == 0) ? s4.x : (k == 1) ? s4.y : (k == 2) ? s4.z : s4.w);
                unsigned r = d >> LOG_NR;
                unsigned pos = atomicAdd(&hist[r], 1u);
                if ((int)pos < CAP) {
                    pk[(size_t)r * CAP + pos] = ((d & (NRP - 1)) << 17) | s;
                } else {
                    unsigned oi = atomicAdd(oc, 1u);
                    if (oi < OVCAP) { ovf[2 * oi] = s; ovf[2 * oi + 1] = d; }
                }
            }
        } else {
            for (int e = base; e < s1; ++e) {
                unsigned d = (unsigned)dst[e];
                unsigned r = d >> LOG_NR;
                unsigned pos = atomicAdd(&hist[r], 1u);
                if ((int)pos < CAP) {
                    pk[(size_t)r * CAP + pos] = ((d & (NRP - 1)) << 17) | (unsigned)src[e];
                } else {
                    unsigned oi = atomicAdd(oc, 1u);
                    if (oi < OVCAP) { ovf[2 * oi] = (unsigned)src[e]; ovf[2 * oi + 1] = d; }
                }
            }
        }
    }
}

// ---------------- process: dense per-range LJ + direct out write -------------
__device__ __forceinline__ void lj_body(unsigned p, float3 xs,
                                        const float* __restrict__ xr,
                                        float* __restrict__ acc) {
    int u = (int)(p >> 17);
    float dx = xr[3 * u + 0] - xs.x;
    float dy = xr[3 * u + 1] - xs.y;
    float dz = xr[3 * u + 2] - xs.z;
    float r2 = dx * dx + dy * dy + dz * dz;
    float rr = sqrtf(r2);
    float inv_norm = 1.0f / fmaxf(rr, 1e-12f);
    float rc = fmaxf(rr, MIN_R);
    float s1 = 1.0f / rc;                      // RC = 1
    float s2 = s1 * s1;
    float s6 = s2 * s2 * s2;
    float F = 4.0f * s6 * (12.0f * s6 - 6.0f) * s1;
    float sc = F * inv_norm;
    atomicAdd(&acc[3 * u + 0], sc * dx);
    atomicAdd(&acc[3 * u + 1], sc * dy);
    atomicAdd(&acc[3 * u + 2], sc * dz);
}

__global__ __launch_bounds__(THR_P) void process_kernel(
    const float* __restrict__ x, const float* __restrict__ v,
    const unsigned* __restrict__ pk, const unsigned* __restrict__ gcur,
    const unsigned* __restrict__ oc, const unsigned* __restrict__ ovf,
    float* __restrict__ out, int n_nodes, int CAP)
{
    __shared__ __align__(16) float acc[S3];
    __shared__ __align__(16) float xr[S3];
    const int r = blockIdx.x, t = threadIdx.x;
    const int xbase = 3 * r * NRP;
    const int xlim = 3 * n_nodes;
    for (int i = t; i < S3; i += THR_P) {
        acc[i] = 0.0f;
        int g = xbase + i;
        xr[i] = (g < xlim) ? x[g] : 0.0f;
    }
    __syncthreads();

    const unsigned* bin = pk + (size_t)r * CAP;
    const int cnt = min((int)gcur[r], CAP);

    // 4-edge batches: coalesced pk load, 4 independent gathers in flight
    for (int i = t * 4; i < cnt; i += THR_P * 4) {
        if (i + 3 < cnt) {
            uint4 q = *(const uint4*)(bin + i);
            float3 a0 = *(const float3*)(x + 3 * (q.x & 0x1FFFFu));
            float3 a1 = *(const float3*)(x + 3 * (q.y & 0x1FFFFu));
            float3 a2 = *(const float3*)(x + 3 * (q.z & 0x1FFFFu));
            float3 a3 = *(const float3*)(x + 3 * (q.w & 0x1FFFFu));
            lj_body(q.x, a0, xr, acc);
            lj_body(q.y, a1, xr, acc);
            lj_body(q.z, a2, xr, acc);
            lj_body(q.w, a3, xr, acc);
        } else {
            for (int e = i; e < cnt; ++e) {
                unsigned p = bin[e];
                float3 xs = *(const float3*)(x + 3 * (p & 0x1FFFFu));
                lj_body(p, xs, xr, acc);
            }
        }
    }

    // overflow replay (normally zero entries)
    const int noc = min((int)*oc, OVCAP);
    for (int i = t; i < noc; i += THR_P) {
        unsigned s = ovf[2 * i], d = ovf[2 * i + 1];
        if ((int)(d >> LOG_NR) == r) {
            unsigned p = ((d & (NRP - 1)) << 17) | s;
            float3 xs = *(const float3*)(x + 3 * s);
            lj_body(p, xs, xr, acc);
        }
    }
    __syncthreads();

    for (int i = t; i < S3; i += THR_P) {
        int g = xbase + i;
        if (g < xlim) out[g] = acc[i] - GAMMA * v[g];
    }
}

// ---------------- fallback path ----------------------------------------------
__global__ void init_out_kernel(const float* __restrict__ v,
                                float* __restrict__ out, int n) {
    int i = blockIdx.x * blockDim.x + threadIdx.x;
    if (i < n) out[i] = -GAMMA * v[i];
}

__global__ void edge_atomic_kernel(const float* __restrict__ x,
                                   const int* __restrict__ src,
                                   const int* __restrict__ dst,
                                   float* __restrict__ out, int n_edges) {
    int e = blockIdx.x * blockDim.x + threadIdx.x;
    if (e < n_edges) {
        int s = src[e], d = dst[e];
        float dx = x[3 * d + 0] - x[3 * s + 0];
        float dy = x[3 * d + 1] - x[3 * s + 1];
        float dz = x[3 * d + 2] - x[3 * s + 2];
        float rr = sqrtf(dx * dx + dy * dy + dz * dz);
        float inv_norm = 1.0f / fmaxf(rr, 1e-12f);
        float rc = fmaxf(rr, MIN_R);
        float s1 = 1.0f / rc;
        float s2 = s1 * s1;
        float s6 = s2 * s2 * s2;
        float F = 4.0f * s6 * (12.0f * s6 - 6.0f) * s1;
        float sc = F * inv_norm;
        unsafeAtomicAdd(&out[3 * d + 0], sc * dx);
        unsafeAtomicAdd(&out[3 * d + 1], sc * dy);
        unsafeAtomicAdd(&out[3 * d + 2], sc * dz);
    }
}

extern "C" void kernel_launch(void* const* d_in, const int* in_sizes, int n_in,
                              void* d_out, int out_size, void* d_ws, size_t ws_size,
                              hipStream_t stream) {
    const float* x   = (const float*)d_in[0];
    const float* v   = (const float*)d_in[1];
    const int*   src = (const int*)d_in[2];
    const int*   dst = (const int*)d_in[3];
    float* out = (float*)d_out;

    const int n_out = out_size;
    const int n_nodes = out_size / 3;
    const int n_edges = in_sizes[2];
    const int R = (n_nodes + NRP - 1) / NRP;

    // bin capacity: mean + 25% headroom, rounded to 256 (uint4-aligned)
    int CAP = ((n_edges / (R > 0 ? R : 1)) * 5 / 4 + 511) & ~255;

    // ws layout: gcur[R] | oc[1] | ovf[2*OVCAP] | (64-align) pk[R*CAP]
    const size_t gcur_off = 0;
    const size_t oc_off   = (size_t)R;
    const size_t ovf_off  = oc_off + 1;
    const size_t pk_byte_off = (((ovf_off + 2 * (size_t)OVCAP) * 4) + 63) & ~(size_t)63;

    // shrink CAP if needed (overflow path catches the spill)
    size_t need = pk_byte_off + (size_t)R * CAP * 4;
    while (CAP > 1024 && need > ws_size) {
        CAP -= 256;
        need = pk_byte_off + (size_t)R * CAP * 4;
    }

    if (n_nodes <= (1 << 17) && R <= RMAX && need <= ws_size) {
        unsigned* gcur = (unsigned*)d_ws + gcur_off;
        unsigned* oc   = (unsigned*)d_ws + oc_off;
        unsigned* ovf  = (unsigned*)d_ws + ovf_off;
        unsigned* pk   = (unsigned*)((char*)d_ws + pk_byte_off);

        hipMemsetAsync(gcur, 0, (size_t)(R + 1) * 4, stream);  // gcur + oc

        int epb = ((n_edges + NB - 1) / NB + 3) & ~3;
        scatter_kernel<<<NB, THR_S, 0, stream>>>(src, dst, gcur, oc, ovf, pk,
                                                 n_edges, epb, R, CAP);
        process_kernel<<<R, THR_P, 0, stream>>>(x, v, pk, gcur, oc, ovf,
                                                out, n_nodes, CAP);
    } else {
        int blk = 256;
        init_out_kernel<<<(n_out + blk - 1) / blk, blk, 0, stream>>>(v, out, n_out);
        edge_atomic_kernel<<<(n_edges + blk - 1) / blk, blk, 0, stream>>>(
            x, src, dst, out, n_edges);
    }
}

// Round 7
// 181.052 us; speedup vs baseline: 1.0250x; 1.0250x over previous
//
#include <hip/hip_runtime.h>

#define GAMMA 0.1f
#define MIN_R 0.1f

#define NRP 128                 // nodes per bin (power of 2)
#define LOG_NR 7
#define S3 (3 * NRP)            // floats per bin slice (384)
#define THR_S 512               // scatter threads
#define THR_P 512               // process threads
#define RMAX 1024               // max bins (n_nodes <= 131072 = 17-bit src)
#define OVCAP 131072            // overflow list capacity (edges)

// ---------------- single-pass segmented scatter ------------------------------
// pk bin r occupies [r*CAP, (r+1)*CAP), CAP = NBS*SEG. Block b owns slots
// [r*CAP + b*SEG, +SEG) of every bin. Slot index from block-local LDS cursor.
__global__ __launch_bounds__(THR_S) void scatter_kernel(
    const int* __restrict__ src, const int* __restrict__ dst,
    unsigned* __restrict__ counts,   // [R][NBS]
    unsigned* __restrict__ oc, unsigned* __restrict__ ovf,
    unsigned* __restrict__ pk,
    int n_edges, int epb, int R, int NBS, int SEG)
{
    __shared__ unsigned cur[RMAX];
    const int b = blockIdx.x, t = threadIdx.x;
    const int CAP = NBS * SEG;
    for (int i = t; i < R; i += THR_S) cur[i] = 0u;
    __syncthreads();

    const int s0 = b * epb;
    const int s1 = min(s0 + epb, n_edges);
    const size_t segb = (size_t)b * SEG;

    for (int base = s0 + t * 4; base < s1; base += THR_S * 4) {
        if (base + 3 < s1) {
            int4 d4 = *(const int4*)(dst + base);
            int4 s4 = *(const int4*)(src + base);
            #pragma unroll
            for (int k = 0; k < 4; ++k) {
                unsigned d = (unsigned)((k == 0) ? d4.x : (k == 1) ? d4.y : (k == 2) ? d4.z : d4.w);
                unsigned s = (unsigned)((k == 0) ? s4.x : (k == 1) ? s4.y : (k == 2) ? s4.z : s4.w);
                unsigned r = d >> LOG_NR;
                unsigned pos = atomicAdd(&cur[r], 1u);
                if ((int)pos < SEG) {
                    pk[(size_t)r * CAP + segb + pos] = ((d & (NRP - 1)) << 17) | s;
                } else {
                    unsigned oi = atomicAdd(oc, 1u);
                    if (oi < OVCAP) { ovf[2 * oi] = s; ovf[2 * oi + 1] = d; }
                }
            }
        } else {
            for (int e = base; e < s1; ++e) {
                unsigned d = (unsigned)dst[e];
                unsigned r = d >> LOG_NR;
                unsigned pos = atomicAdd(&cur[r], 1u);
                if ((int)pos < SEG) {
                    pk[(size_t)r * CAP + segb + pos] = ((d & (NRP - 1)) << 17) | (unsigned)src[e];
                } else {
                    unsigned oi = atomicAdd(oc, 1u);
                    if (oi < OVCAP) { ovf[2 * oi] = (unsigned)src[e]; ovf[2 * oi + 1] = d; }
                }
            }
        }
    }
    __syncthreads();
    for (int i = t; i < R; i += THR_S)
        counts[(size_t)i * NBS + b] = min(cur[i], (unsigned)SEG);
}

// ---------------- process: dense per-bin LJ + direct out write ---------------
__device__ __forceinline__ void lj_body(unsigned p, float3 xs,
                                        const float* __restrict__ xr,
                                        float* __restrict__ acc) {
    int u = (int)(p >> 17);
    float dx = xr[3 * u + 0] - xs.x;
    float dy = xr[3 * u + 1] - xs.y;
    float dz = xr[3 * u + 2] - xs.z;
    float r2 = dx * dx + dy * dy + dz * dz;
    float rr = sqrtf(r2);
    float inv_norm = 1.0f / fmaxf(rr, 1e-12f);
    float rc = fmaxf(rr, MIN_R);
    float s1 = 1.0f / rc;                      // RC = 1
    float s2 = s1 * s1;
    float s6 = s2 * s2 * s2;
    float F = 4.0f * s6 * (12.0f * s6 - 6.0f) * s1;
    float sc = F * inv_norm;
    atomicAdd(&acc[3 * u + 0], sc * dx);
    atomicAdd(&acc[3 * u + 1], sc * dy);
    atomicAdd(&acc[3 * u + 2], sc * dz);
}

__global__ __launch_bounds__(THR_P) void process_kernel(
    const float* __restrict__ x, const float* __restrict__ v,
    const unsigned* __restrict__ pk, const unsigned* __restrict__ counts,
    const unsigned* __restrict__ oc, const unsigned* __restrict__ ovf,
    float* __restrict__ out, int n_nodes, int NBS, int SEG)
{
    __shared__ __align__(16) float acc[S3];
    __shared__ __align__(16) float xr[S3];
    const int r = blockIdx.x, t = threadIdx.x;
    const int CAP = NBS * SEG;
    const int TPS = THR_P / NBS;               // threads per segment (2 or 4)
    const int xbase = 3 * r * NRP;
    const int xlim = 3 * n_nodes;
    for (int i = t; i < S3; i += THR_P) {
        acc[i] = 0.0f;
        int g = xbase + i;
        xr[i] = (g < xlim) ? x[g] : 0.0f;
    }
    __syncthreads();

    // segment phase: thread t works on segment s = t/TPS, entries i = lane (mod TPS)
    {
        const int s = t / TPS;
        const int lane = t - s * TPS;
        const int cnt = (int)counts[(size_t)r * NBS + s];
        const unsigned* segp = pk + (size_t)r * CAP + (size_t)s * SEG;
        int i = lane;
        if (i < cnt) {
            unsigned p = segp[i];
            for (;;) {
                int inext = i + TPS;
                unsigned pn = (inext < cnt) ? segp[inext] : 0u;   // prefetch
                float3 xs = *(const float3*)(x + 3 * (p & 0x1FFFFu));
                lj_body(p, xs, xr, acc);
                if (inext >= cnt) break;
                p = pn; i = inext;
            }
        }
    }

    // overflow replay (normally zero entries)
    const int noc = min((int)*oc, OVCAP);
    for (int i = t; i < noc; i += THR_P) {
        unsigned s = ovf[2 * i], d = ovf[2 * i + 1];
        if ((int)(d >> LOG_NR) == r) {
            unsigned p = ((d & (NRP - 1)) << 17) | s;
            float3 xs = *(const float3*)(x + 3 * s);
            lj_body(p, xs, xr, acc);
        }
    }
    __syncthreads();

    for (int i = t; i < S3; i += THR_P) {
        int g = xbase + i;
        if (g < xlim) out[g] = acc[i] - GAMMA * v[g];
    }
}

// ---------------- fallback path ----------------------------------------------
__global__ void init_out_kernel(const float* __restrict__ v,
                                float* __restrict__ out, int n) {
    int i = blockIdx.x * blockDim.x + threadIdx.x;
    if (i < n) out[i] = -GAMMA * v[i];
}

__global__ void edge_atomic_kernel(const float* __restrict__ x,
                                   const int* __restrict__ src,
                                   const int* __restrict__ dst,
                                   float* __restrict__ out, int n_edges) {
    int e = blockIdx.x * blockDim.x + threadIdx.x;
    if (e < n_edges) {
        int s = src[e], d = dst[e];
        float dx = x[3 * d + 0] - x[3 * s + 0];
        float dy = x[3 * d + 1] - x[3 * s + 1];
        float dz = x[3 * d + 2] - x[3 * s + 2];
        float rr = sqrtf(dx * dx + dy * dy + dz * dz);
        float inv_norm = 1.0f / fmaxf(rr, 1e-12f);
        float rc = fmaxf(rr, MIN_R);
        float s1 = 1.0f / rc;
        float s2 = s1 * s1;
        float s6 = s2 * s2 * s2;
        float F = 4.0f * s6 * (12.0f * s6 - 6.0f) * s1;
        float sc = F * inv_norm;
        unsafeAtomicAdd(&out[3 * d + 0], sc * dx);
        unsafeAtomicAdd(&out[3 * d + 1], sc * dy);
        unsafeAtomicAdd(&out[3 * d + 2], sc * dz);
    }
}

extern "C" void kernel_launch(void* const* d_in, const int* in_sizes, int n_in,
                              void* d_out, int out_size, void* d_ws, size_t ws_size,
                              hipStream_t stream) {
    const float* x   = (const float*)d_in[0];
    const float* v   = (const float*)d_in[1];
    const int*   src = (const int*)d_in[2];
    const int*   dst = (const int*)d_in[3];
    float* out = (float*)d_out;

    const int n_out = out_size;
    const int n_nodes = out_size / 3;
    const int n_edges = in_sizes[2];
    const int R = (n_nodes + NRP - 1) / NRP;

    // ws-size-adaptive (NBS, SEG) ladder, largest overflow margin first.
    // lambda = edges per (block,bin) = E/(NBS*R); SEG chosen >= lambda + ~3sigma.
    const int cfg_nbs[5] = {256, 256, 128, 128, 128};
    const int cfg_seg[5] = {40,  32,  48,  44,  40};
    int NBS = 0, SEG = 0;
    size_t pk_byte_off = 0;
    for (int c = 0; c < 5; ++c) {
        int nbs = cfg_nbs[c], seg = cfg_seg[c];
        size_t tables = ((size_t)R * nbs + 1 + 2 * (size_t)OVCAP) * 4;
        size_t pko = (tables + 63) & ~(size_t)63;
        size_t need = pko + (size_t)R * nbs * seg * 4;
        if (need <= ws_size) { NBS = nbs; SEG = seg; pk_byte_off = pko; break; }
    }

    if (n_nodes <= (1 << 17) && R <= RMAX && NBS > 0) {
        unsigned* counts = (unsigned*)d_ws;                  // R*NBS
        unsigned* oc     = counts + (size_t)R * NBS;         // 1
        unsigned* ovf    = oc + 1;                           // 2*OVCAP
        unsigned* pk     = (unsigned*)((char*)d_ws + pk_byte_off);

        hipMemsetAsync(oc, 0, 4, stream);

        int epb = ((n_edges + NBS - 1) / NBS + 3) & ~3;
        scatter_kernel<<<NBS, THR_S, 0, stream>>>(src, dst, counts, oc, ovf, pk,
                                                  n_edges, epb, R, NBS, SEG);
        process_kernel<<<R, THR_P, 0, stream>>>(x, v, pk, counts, oc, ovf,
                                                out, n_nodes, NBS, SEG);
    } else {
        int blk = 256;
        init_out_kernel<<<(n_out + blk - 1) / blk, blk, 0, stream>>>(v, out, n_out);
        edge_atomic_kernel<<<(n_edges + blk - 1) / blk, blk, 0, stream>>>(
            x, src, dst, out, n_edges);
    }
}

// Round 8
// 177.506 us; speedup vs baseline: 1.0455x; 1.0200x over previous
//
#include <hip/hip_runtime.h>

#define GAMMA 0.1f
#define MIN_R 0.1f

#define NRP 128                 // nodes per bin (power of 2)
#define LOG_NR 7
#define S3 (3 * NRP)            // floats per bin slice (384)
#define SEG 32                  // slots per (block,bin) segment (power of 2)
#define LOG_SEG 5
#define THR_S 1024              // scatter threads
#define THR_P 512               // process threads
#define RMAX 1024               // max bins (n_nodes <= 131072 = 17-bit src)
#define NBSMAX 1024
#define OVCAP 131072            // overflow list capacity (edges)

// ---------------- single-pass segmented scatter ------------------------------
// pk bin r occupies [r*CAP, (r+1)*CAP), CAP = NBS*SEG. Block b owns slots
// [r*CAP + b*SEG, +SEG). Slot index from block-local LDS cursor.
__global__ __launch_bounds__(THR_S) void scatter_kernel(
    const int* __restrict__ src, const int* __restrict__ dst,
    unsigned* __restrict__ counts,   // [R][NBS]
    unsigned* __restrict__ oc, unsigned* __restrict__ ovf,
    unsigned* __restrict__ pk,
    int n_edges, int epb, int R, int NBS)
{
    __shared__ unsigned cur[RMAX];
    const int b = blockIdx.x, t = threadIdx.x;
    const size_t CAP = (size_t)NBS << LOG_SEG;
    for (int i = t; i < R; i += THR_S) cur[i] = 0u;
    __syncthreads();

    const int s0 = b * epb;
    const int s1 = min(s0 + epb, n_edges);
    const size_t segb = (size_t)b << LOG_SEG;

    for (int base = s0 + t * 4; base < s1; base += THR_S * 4) {
        if (base + 3 < s1) {
            int4 d4 = *(const int4*)(dst + base);
            int4 s4 = *(const int4*)(src + base);
            #pragma unroll
            for (int k = 0; k < 4; ++k) {
                unsigned d = (unsigned)((k == 0) ? d4.x : (k == 1) ? d4.y : (k == 2) ? d4.z : d4.w);
                unsigned s = (unsigned)((k == 0) ? s4.x : (k == 1) ? s4.y : (k == 2) ? s4.z : s4.w);
                unsigned r = d >> LOG_NR;
                unsigned pos = atomicAdd(&cur[r], 1u);
                if (pos < SEG) {
                    pk[(size_t)r * CAP + segb + pos] = ((d & (NRP - 1)) << 17) | s;
                } else {
                    unsigned oi = atomicAdd(oc, 1u);
                    if (oi < OVCAP) { ovf[2 * oi] = s; ovf[2 * oi + 1] = d; }
                }
            }
        } else {
            for (int e = base; e < s1; ++e) {
                unsigned d = (unsigned)dst[e];
                unsigned r = d >> LOG_NR;
                unsigned pos = atomicAdd(&cur[r], 1u);
                if (pos < SEG) {
                    pk[(size_t)r * CAP + segb + pos] = ((d & (NRP - 1)) << 17) | (unsigned)src[e];
                } else {
                    unsigned oi = atomicAdd(oc, 1u);
                    if (oi < OVCAP) { ovf[2 * oi] = (unsigned)src[e]; ovf[2 * oi + 1] = d; }
                }
            }
        }
    }
    __syncthreads();
    for (int i = t; i < R; i += THR_S)
        counts[(size_t)i * NBS + b] = min(cur[i], (unsigned)SEG);
}

// ---------------- process: dense per-bin LJ + direct out write ---------------
__device__ __forceinline__ void lj_body(unsigned p, float3 xs,
                                        const float* __restrict__ xr,
                                        float* __restrict__ acc) {
    int u = (int)(p >> 17);
    float dx = xr[3 * u + 0] - xs.x;
    float dy = xr[3 * u + 1] - xs.y;
    float dz = xr[3 * u + 2] - xs.z;
    float r2 = dx * dx + dy * dy + dz * dz;
    float rr = sqrtf(r2);
    float inv_norm = 1.0f / fmaxf(rr, 1e-12f);
    float rc = fmaxf(rr, MIN_R);
    float s1 = 1.0f / rc;                      // RC = 1
    float s2 = s1 * s1;
    float s6 = s2 * s2 * s2;
    float F = 4.0f * s6 * (12.0f * s6 - 6.0f) * s1;
    float sc = F * inv_norm;
    atomicAdd(&acc[3 * u + 0], sc * dx);
    atomicAdd(&acc[3 * u + 1], sc * dy);
    atomicAdd(&acc[3 * u + 2], sc * dz);
}

__global__ __launch_bounds__(THR_P) void process_kernel(
    const float* __restrict__ x, const float* __restrict__ v,
    const unsigned* __restrict__ pk, const unsigned* __restrict__ counts,
    const unsigned* __restrict__ oc, const unsigned* __restrict__ ovf,
    float* __restrict__ out, int n_nodes, int NBS)
{
    __shared__ __align__(16) float acc[S3];
    __shared__ __align__(16) float xr[S3];
    __shared__ unsigned cnts[NBSMAX];
    const int r = blockIdx.x, t = threadIdx.x;
    const int CAP = NBS << LOG_SEG;
    const int xbase = 3 * r * NRP;
    const int xlim = 3 * n_nodes;
    for (int i = t; i < S3; i += THR_P) {
        acc[i] = 0.0f;
        int g = xbase + i;
        xr[i] = (g < xlim) ? x[g] : 0.0f;
    }
    for (int i = t; i < NBS; i += THR_P)
        cnts[i] = counts[(size_t)r * NBS + i];
    __syncthreads();

    // wave-coalesced uint4 scan over all segments of this bin
    const unsigned* bin = pk + (size_t)r * CAP;
    for (int sb = t * 4; sb < CAP; sb += THR_P * 4) {
        // slots sb..sb+3 lie inside one segment (SEG=32, sb % 4 == 0)
        const int cnt = (int)cnts[sb >> LOG_SEG];
        const int idx0 = sb & (SEG - 1);
        if (idx0 < cnt) {
            uint4 q = *(const uint4*)(bin + sb);
            int nv = cnt - idx0;               // 1..4 valid entries
            float3 a0 = *(const float3*)(x + 3 * (q.x & 0x1FFFFu));
            float3 a1, a2, a3;
            if (nv > 1) a1 = *(const float3*)(x + 3 * (q.y & 0x1FFFFu));
            if (nv > 2) a2 = *(const float3*)(x + 3 * (q.z & 0x1FFFFu));
            if (nv > 3) a3 = *(const float3*)(x + 3 * (q.w & 0x1FFFFu));
            lj_body(q.x, a0, xr, acc);
            if (nv > 1) lj_body(q.y, a1, xr, acc);
            if (nv > 2) lj_body(q.z, a2, xr, acc);
            if (nv > 3) lj_body(q.w, a3, xr, acc);
        }
    }

    // overflow replay (normally zero entries)
    const int noc = min((int)*oc, OVCAP);
    for (int i = t; i < noc; i += THR_P) {
        unsigned s = ovf[2 * i], d = ovf[2 * i + 1];
        if ((int)(d >> LOG_NR) == r) {
            unsigned p = ((d & (NRP - 1)) << 17) | s;
            float3 xs = *(const float3*)(x + 3 * s);
            lj_body(p, xs, xr, acc);
        }
    }
    __syncthreads();

    for (int i = t; i < S3; i += THR_P) {
        int g = xbase + i;
        if (g < xlim) out[g] = acc[i] - GAMMA * v[g];
    }
}

// ---------------- fallback path ----------------------------------------------
__global__ void init_out_kernel(const float* __restrict__ v,
                                float* __restrict__ out, int n) {
    int i = blockIdx.x * blockDim.x + threadIdx.x;
    if (i < n) out[i] = -GAMMA * v[i];
}

__global__ void edge_atomic_kernel(const float* __restrict__ x,
                                   const int* __restrict__ src,
                                   const int* __restrict__ dst,
                                   float* __restrict__ out, int n_edges) {
    int e = blockIdx.x * blockDim.x + threadIdx.x;
    if (e < n_edges) {
        int s = src[e], d = dst[e];
        float dx = x[3 * d + 0] - x[3 * s + 0];
        float dy = x[3 * d + 1] - x[3 * s + 1];
        float dz = x[3 * d + 2] - x[3 * s + 2];
        float rr = sqrtf(dx * dx + dy * dy + dz * dz);
        float inv_norm = 1.0f / fmaxf(rr, 1e-12f);
        float rc = fmaxf(rr, MIN_R);
        float s1 = 1.0f / rc;
        float s2 = s1 * s1;
        float s6 = s2 * s2 * s2;
        float F = 4.0f * s6 * (12.0f * s6 - 6.0f) * s1;
        float sc = F * inv_norm;
        unsafeAtomicAdd(&out[3 * d + 0], sc * dx);
        unsafeAtomicAdd(&out[3 * d + 1], sc * dy);
        unsafeAtomicAdd(&out[3 * d + 2], sc * dz);
    }
}

extern "C" void kernel_launch(void* const* d_in, const int* in_sizes, int n_in,
                              void* d_out, int out_size, void* d_ws, size_t ws_size,
                              hipStream_t stream) {
    const float* x   = (const float*)d_in[0];
    const float* v   = (const float*)d_in[1];
    const int*   src = (const int*)d_in[2];
    const int*   dst = (const int*)d_in[3];
    float* out = (float*)d_out;

    const int n_out = out_size;
    const int n_nodes = out_size / 3;
    const int n_edges = in_sizes[2];
    const int R = (n_nodes + NRP - 1) / NRP;

    // pick NBS so lambda = E/(R*NBS) <= 20 (SEG=32 is then >= +3 sigma)
    int NBS = 256;
    while (NBS < NBSMAX && n_edges > 20 * (size_t)R * NBS) NBS <<= 1;

    size_t tables = ((size_t)R * NBS + 1 + 2 * (size_t)OVCAP) * 4;
    size_t pk_byte_off = (tables + 63) & ~(size_t)63;
    size_t need = pk_byte_off + ((size_t)R * NBS << LOG_SEG) * 4;

    if (n_nodes <= (1 << 17) && R <= RMAX && need <= ws_size) {
        unsigned* counts = (unsigned*)d_ws;                  // R*NBS
        unsigned* oc     = counts + (size_t)R * NBS;         // 1
        unsigned* ovf    = oc + 1;                           // 2*OVCAP
        unsigned* pk     = (unsigned*)((char*)d_ws + pk_byte_off);

        hipMemsetAsync(oc, 0, 4, stream);

        int epb = ((n_edges + NBS - 1) / NBS + 3) & ~3;
        scatter_kernel<<<NBS, THR_S, 0, stream>>>(src, dst, counts, oc, ovf, pk,
                                                  n_edges, epb, R, NBS);
        process_kernel<<<R, THR_P, 0, stream>>>(x, v, pk, counts, oc, ovf,
                                                out, n_nodes, NBS);
    } else {
        int blk = 256;
        init_out_kernel<<<(n_out + blk - 1) / blk, blk, 0, stream>>>(v, out, n_out);
        edge_atomic_kernel<<<(n_edges + blk - 1) / blk, blk, 0, stream>>>(
            x, src, dst, out, n_edges);
    }
}